// Round 5
// baseline (296.076 us; speedup 1.0000x reference)
//
#include <hip/hip_runtime.h>

#define SEQ 4096
#define DIM 1280
#define NH 16
#define HD 80
#define HQ 96
#define TDIM 3840

// softmax scale (1/sqrt(80)) * log2(e), folded into Q at repack
#define QSC 0.16129842980505168f

typedef __bf16 bf16x8 __attribute__((ext_vector_type(8)));
typedef __bf16 bf16x4 __attribute__((ext_vector_type(4)));
typedef float f32x4 __attribute__((ext_vector_type(4)));

__device__ __forceinline__ unsigned short f2bf(float f) {
  unsigned int u = __builtin_bit_cast(unsigned int, f);
  u += 0x7FFF + ((u >> 16) & 1);
  return (unsigned short)(u >> 16);
}
__device__ __forceinline__ float bf2f(unsigned short b) {
  unsigned int u = ((unsigned int)b) << 16;
  return __builtin_bit_cast(float, u);
}
__device__ __forceinline__ unsigned int cvtpk(float a, float b) {
  unsigned int r;
  asm("v_cvt_pk_bf16_f32 %0, %1, %2" : "=v"(r) : "v"(a), "v"(b));
  return r;
}

__device__ __forceinline__ void gload_lds16(const void* g, void* l) {
  __builtin_amdgcn_global_load_lds(
      (const __attribute__((address_space(1))) unsigned int*)g,
      (__attribute__((address_space(3))) unsigned int*)l, 16, 0, 0);
}

// ---------------- fp32 -> bf16 convert (vectorized) ----------------
__global__ void cvt_bf16(const float* __restrict__ in, unsigned short* __restrict__ out, int n4) {
  int i = blockIdx.x * 256 + threadIdx.x;
  if (i >= n4) return;
  float4 f = ((const float4*)in)[i];
  ushort4 o;
  o.x = f2bf(f.x); o.y = f2bf(f.y); o.z = f2bf(f.z); o.w = f2bf(f.w);
  ((ushort4*)out)[i] = o;
}

// ---------------- cos/sin table ----------------
__global__ void trig_tab(const float* __restrict__ rope, float* __restrict__ ct,
                         float* __restrict__ st, int n) {
  int i = blockIdx.x * 256 + threadIdx.x;
  if (i >= n) return;
  float v = rope[i];
  ct[i] = cosf(v);
  st[i] = sinf(v);
}

// ---------------- GEMM: C = A(MxK) @ B(NxK)^T + bias ----------------
template <int F32OUT>
__global__ __launch_bounds__(256) void gemm_bt(const unsigned short* __restrict__ A,
                                               const unsigned short* __restrict__ B,
                                               const float* __restrict__ bias,
                                               void* __restrict__ Cout, int M, int N, int K) {
  __shared__ unsigned short As[4096];
  __shared__ unsigned short Bs[4096];
  const int t = threadIdx.x;
  const int l = t & 63, w = t >> 6;
  const int row16 = l & 15, kg = l >> 4;
  const int brow = blockIdx.y * 128, bcol = blockIdx.x * 128;
  const int wr = w >> 1, wc = w & 1;
  f32x4 acc[4][4] = {};
  const size_t Ks = (size_t)K;
  const unsigned short* Ag = A + (brow + (t >> 2)) * Ks + (t & 3) * 8;
  const unsigned short* Bg = B + (bcol + (t >> 2)) * Ks + (t & 3) * 8;
  unsigned short* AsW = As + w * 512;
  unsigned short* BsW = Bs + w * 512;
  const int nk = K >> 5;
  for (int kt = 0; kt < nk; ++kt) {
    const unsigned short* a = Ag + kt * 32;
    const unsigned short* b = Bg + kt * 32;
    gload_lds16(a, AsW);
    gload_lds16(a + 64 * Ks, AsW + 2048);
    gload_lds16(b, BsW);
    gload_lds16(b + 64 * Ks, BsW + 2048);
    __syncthreads();
    bf16x8 af[4], bfr[4];
#pragma unroll
    for (int m = 0; m < 4; ++m)
      af[m] = *(const bf16x8*)&As[(wr * 64 + m * 16 + row16) * 32 + kg * 8];
#pragma unroll
    for (int n = 0; n < 4; ++n)
      bfr[n] = *(const bf16x8*)&Bs[(wc * 64 + n * 16 + row16) * 32 + kg * 8];
#pragma unroll
    for (int m = 0; m < 4; ++m)
#pragma unroll
      for (int n = 0; n < 4; ++n)
        acc[m][n] = __builtin_amdgcn_mfma_f32_16x16x32_bf16(af[m], bfr[n], acc[m][n], 0, 0, 0);
    __syncthreads();
  }
#pragma unroll
  for (int n = 0; n < 4; ++n) {
    const int col = bcol + wc * 64 + n * 16 + row16;
    const float bv = bias[col];
#pragma unroll
    for (int m = 0; m < 4; ++m) {
      const int row = brow + wr * 64 + m * 16 + kg * 4;
#pragma unroll
      for (int r = 0; r < 4; ++r) {
        float v = acc[m][n][r] + bv;
        if (F32OUT)
          ((float*)Cout)[(size_t)(row + r) * N + col] = v;
        else
          ((unsigned short*)Cout)[(size_t)(row + r) * N + col] = f2bf(v);
      }
    }
  }
}

// ---------------- RoPE + repack Q,K -> [h][s][96]; Q pre-scaled ----------------
__global__ __launch_bounds__(256) void rope_qk2(const unsigned short* __restrict__ Y,
                                                const float* __restrict__ ct,
                                                const float* __restrict__ st,
                                                unsigned short* __restrict__ Qr,
                                                unsigned short* __restrict__ Kr) {
  const int s = blockIdx.x, tid = threadIdx.x;
  const unsigned short* yq = Y + (size_t)s * TDIM;
  const unsigned short* yk = yq + DIM;
  for (int i = tid; i < 640; i += 256) {
    const int h = i / 40, j = i - h * 40;
    const float c0 = ct[s * HD + j], c1 = ct[s * HD + j + 40];
    const float s0 = st[s * HD + j], s1 = st[s * HD + j + 40];
    const float q0 = bf2f(yq[h * HD + j]), q1 = bf2f(yq[h * HD + j + 40]);
    const float k0 = bf2f(yk[h * HD + j]), k1 = bf2f(yk[h * HD + j + 40]);
    const size_t o = ((size_t)h * SEQ + s) * HQ;
    Qr[o + j] = f2bf((q0 * c0 - q1 * s0) * QSC);
    Qr[o + j + 40] = f2bf((q1 * c1 + q0 * s1) * QSC);
    Kr[o + j] = f2bf(k0 * c0 - k1 * s0);
    Kr[o + j + 40] = f2bf(k1 * c1 + k0 * s1);
  }
  {  // zero pad d = 80..95 for all 16 heads
    const int h = tid >> 4, dp = 80 + (tid & 15);
    const size_t o = ((size_t)h * SEQ + s) * HQ + dp;
    Qr[o] = 0;
    Kr[o] = 0;
  }
}

// ---------------- V transpose -> permuted image Vp[h][d][4096] ----------------
// Within each 64-s tile: s = ks*32 + b*16 + kg*4 + r stored at granule
// g = (kg*2+ks) ^ (d&7), sub = b*4 + r. Staged linearly into LDS, the attn
// kernel's b128 read (granule (kg*2+ks)^(row16&7)) then lands MFMA slot j at
// s = 32ks + (j>>2)*16 + kg*4 + (j&3) -- the same k-map used to pack P.
__global__ __launch_bounds__(256) void vtrans3(const unsigned short* __restrict__ Y,
                                               unsigned short* __restrict__ Vp) {
  __shared__ unsigned short tile[64][128];
  const int h = blockIdx.x, s0 = blockIdx.y * 64, tid = threadIdx.x;
  const unsigned short* src = Y + 2 * DIM + h * HD;
  for (int u = tid; u < 640; u += 256) {
    const int s = u / 10, j = u - s * 10;
    uint4 v = *(const uint4*)(src + (size_t)(s0 + s) * TDIM + j * 8);
    *(uint4*)&tile[s][(j ^ ((s >> 3) & 7)) << 3] = v;
  }
  __syncthreads();
  for (int u = tid; u < 640; u += 256) {
    const int d = u >> 3, g = u & 7;
    const int gl = g ^ (d & 7);
    const int base_s = (gl & 1) * 32 + (gl >> 1) * 4;
    unsigned short tmp[8];
#pragma unroll
    for (int sub = 0; sub < 8; ++sub) {
      const int s = base_s + (sub >> 2) * 16 + (sub & 3);
      tmp[sub] = tile[s][(((d >> 3) ^ ((s >> 3) & 7)) << 3) + (d & 7)];
    }
    *(uint4*)(Vp + (size_t)(h * HD + d) * SEQ + s0 + g * 8) = *(uint4*)tmp;
  }
}

// ---------------- Flash attention v5: 4 waves x 32 q, lean conflict-free LDS ----
// grid: 512 blocks; h = bid&15 (XCD affinity). K LDS: chunk-major [12 ci][64 s][16B]
// (reads are 256B-contiguous per 16-lane phase = conflict-free, no padding).
// V LDS: [80 d][8 granules][16B] from the pre-permuted Vp image.
__global__ __launch_bounds__(256, 3) void attn5(const unsigned short* __restrict__ Qr,
                                                const unsigned short* __restrict__ Kr,
                                                const unsigned short* __restrict__ Vp,
                                                unsigned short* __restrict__ Ob) {
  constexpr int KBYT = 12288;
  constexpr int VBYT = 10240;
  constexpr int BUFB = KBYT + VBYT;  // 22528
  __shared__ char smem[2 * BUFB];

  const int tid = threadIdx.x;
  const int l = tid & 63, w = tid >> 6;
  const int row16 = l & 15, kg = l >> 4;
  const int bid = blockIdx.x;
  const int h = bid & 15;
  const int q0 = (bid >> 4) * 128 + w * 32;
  const size_t hs = (size_t)h * SEQ;

  const unsigned short* Qh = Qr + hs * HQ;
  const char* Kh = (const char*)(Kr + hs * HQ);
  const char* Vh = (const char*)(Vp + (size_t)h * HD * SEQ);

  // staging: 1408 16B-units (768 K + 640 V); unit u = tid + 256*i
  unsigned soff[6], sdst[6];
  bool isk[6];
  const int cnt = (tid < 128) ? 6 : 5;
#pragma unroll
  for (int i = 0; i < 6; ++i) {
    const int u = tid + 256 * i;
    if (u < 768) {  // K unit: chunk ci = u>>6 of key s = u&63
      soff[i] = (u & 63) * 192 + (u >> 6) * 16;
      isk[i] = true;
    } else {  // V unit: granule g = v&7 of d-row v>>3
      const int v = u - 768;
      soff[i] = (v >> 3) * 8192 + (v & 7) * 16;
      isk[i] = false;
    }
    sdst[i] = u << 4;
  }
  auto STAGE = [&](int t, int bb) {
    const char* kb = Kh + (size_t)t * 12288;
    const char* vb = Vh + (size_t)t * 128;
#pragma unroll
    for (int i = 0; i < 6; ++i)
      if (i < cnt) gload_lds16((isk[i] ? kb : vb) + soff[i], smem + bb + sdst[i]);
  };

  // LDS read bases (tile-invariant)
  const int kbase = row16 * 16;  // + (4c+kg)*1024 + nb*256
  int vb_[2];
#pragma unroll
  for (int ks = 0; ks < 2; ++ks)
    vb_[ks] = KBYT + row16 * 128 + ((((kg << 1) | ks) ^ (row16 & 7)) << 4);  // + n5*2048

  // Q fragments (B-operand of swapped QK^T): q = q0 + qb*16 + row16
  bf16x8 qf[2][3];
#pragma unroll
  for (int qb = 0; qb < 2; ++qb)
#pragma unroll
    for (int c = 0; c < 3; ++c)
      qf[qb][c] = *(const bf16x8*)&Qh[(size_t)(q0 + qb * 16 + row16) * HQ + c * 32 + kg * 8];

  union { bf16x8 v; unsigned int u[4]; } ones;
  ones.u[0] = ones.u[1] = ones.u[2] = ones.u[3] = 0x3F803F80u;

  float m_run[2] = {-3.0e38f, -3.0e38f};
  f32x4 oacc[2][6] = {};  // [qb][d-block 0..4, 5 = row-sum l]

  STAGE(0, 0);
  __syncthreads();

#pragma unroll 1
  for (int t = 0; t < SEQ / 64; ++t) {
    const int cur = t & 1;
    if (t + 1 < SEQ / 64) STAGE(t + 1, (cur ^ 1) * BUFB);
    const char* B = smem + cur * BUFB;
    // ---- QK^T: per d-chunk c, load 4 K-frags then 8 MFMAs ----
    f32x4 sacc[2][4] = {};
#pragma unroll
    for (int c = 0; c < 3; ++c) {
      bf16x8 kf[4];
      const char* kc = B + (4 * c + kg) * 1024 + kbase;
#pragma unroll
      for (int nb = 0; nb < 4; ++nb) kf[nb] = *(const bf16x8*)(kc + nb * 256);
      __builtin_amdgcn_s_setprio(1);
#pragma unroll
      for (int qb = 0; qb < 2; ++qb)
#pragma unroll
        for (int nb = 0; nb < 4; ++nb)
          sacc[qb][nb] =
              __builtin_amdgcn_mfma_f32_16x16x32_bf16(kf[nb], qf[qb][c], sacc[qb][nb], 0, 0, 0);
      __builtin_amdgcn_s_setprio(0);
    }
    // ---- V fragments (one b128 per (n5, ks)) ----
    bf16x8 vf[5][2];
#pragma unroll
    for (int n5 = 0; n5 < 5; ++n5)
#pragma unroll
      for (int ks = 0; ks < 2; ++ks) vf[n5][ks] = *(const bf16x8*)(B + vb_[ks] + n5 * 2048);
    // ---- per-lane softmax (q = row16), cross-lane only over kg ----
    float pmax[2];
#pragma unroll
    for (int qb = 0; qb < 2; ++qb) {
      float a0 = fmaxf(fmaxf(sacc[qb][0][0], sacc[qb][0][1]), fmaxf(sacc[qb][0][2], sacc[qb][0][3]));
      float a1 = fmaxf(fmaxf(sacc[qb][1][0], sacc[qb][1][1]), fmaxf(sacc[qb][1][2], sacc[qb][1][3]));
      float a2 = fmaxf(fmaxf(sacc[qb][2][0], sacc[qb][2][1]), fmaxf(sacc[qb][2][2], sacc[qb][2][3]));
      float a3 = fmaxf(fmaxf(sacc[qb][3][0], sacc[qb][3][1]), fmaxf(sacc[qb][3][2], sacc[qb][3][3]));
      float m0 = fmaxf(fmaxf(a0, a1), fmaxf(a2, a3));
      m0 = fmaxf(m0, __shfl_xor(m0, 16, 64));
      m0 = fmaxf(m0, __shfl_xor(m0, 32, 64));
      pmax[qb] = m0;
    }
    if (!__all((pmax[0] - m_run[0] <= 8.0f) & (pmax[1] - m_run[1] <= 8.0f))) {
#pragma unroll
      for (int qb = 0; qb < 2; ++qb) {
        const float mn = fmaxf(m_run[qb], pmax[qb]);
        const float fac = __builtin_amdgcn_exp2f(m_run[qb] - mn);
        m_run[qb] = mn;
#pragma unroll
        for (int n6 = 0; n6 < 6; ++n6)
#pragma unroll
          for (int r = 0; r < 4; ++r) oacc[qb][n6][r] *= fac;
      }
    }
#pragma unroll
    for (int qb = 0; qb < 2; ++qb)
#pragma unroll
      for (int nb = 0; nb < 4; ++nb)
#pragma unroll
        for (int r = 0; r < 4; ++r)
          sacc[qb][nb][r] = __builtin_amdgcn_exp2f(sacc[qb][nb][r] - m_run[qb]);
    // ---- pack P -> bf16 (k-map matches Vp image) and PV + row-sum ----
    __builtin_amdgcn_s_setprio(1);
#pragma unroll
    for (int qb = 0; qb < 2; ++qb)
#pragma unroll
      for (int ks = 0; ks < 2; ++ks) {
        union { bf16x8 v; unsigned int u[4]; } pf;
        pf.u[0] = cvtpk(sacc[qb][2 * ks][0], sacc[qb][2 * ks][1]);
        pf.u[1] = cvtpk(sacc[qb][2 * ks][2], sacc[qb][2 * ks][3]);
        pf.u[2] = cvtpk(sacc[qb][2 * ks + 1][0], sacc[qb][2 * ks + 1][1]);
        pf.u[3] = cvtpk(sacc[qb][2 * ks + 1][2], sacc[qb][2 * ks + 1][3]);
#pragma unroll
        for (int n5 = 0; n5 < 5; ++n5)
          oacc[qb][n5] =
              __builtin_amdgcn_mfma_f32_16x16x32_bf16(vf[n5][ks], pf.v, oacc[qb][n5], 0, 0, 0);
        oacc[qb][5] = __builtin_amdgcn_mfma_f32_16x16x32_bf16(ones.v, pf.v, oacc[qb][5], 0, 0, 0);
      }
    __builtin_amdgcn_s_setprio(0);
    __syncthreads();
  }
  // ---- epilogue: d = n5*16 + kg*4 + r, q = q0 + qb*16 + row16 ----
#pragma unroll
  for (int qb = 0; qb < 2; ++qb) {
    const float rl = 1.0f / oacc[qb][5][0];
    unsigned short* orow = Ob + (size_t)(q0 + qb * 16 + row16) * DIM + h * HD + kg * 4;
#pragma unroll
    for (int n5 = 0; n5 < 5; ++n5) {
      ushort4 o;
      o.x = f2bf(oacc[qb][n5][0] * rl);
      o.y = f2bf(oacc[qb][n5][1] * rl);
      o.z = f2bf(oacc[qb][n5][2] * rl);
      o.w = f2bf(oacc[qb][n5][3] * rl);
      *(ushort4*)(orow + n5 * 16) = o;
    }
  }
}

// ---------------- host ----------------
extern "C" void kernel_launch(void* const* d_in, const int* in_sizes, int n_in, void* d_out,
                              int out_size, void* d_ws, size_t ws_size, hipStream_t stream) {
  (void)in_sizes; (void)n_in; (void)out_size; (void)ws_size;
  const float* hidden = (const float*)d_in[0];
  const float* rope = (const float*)d_in[2];
  const float* qkv_w = (const float*)d_in[3];
  const float* qkv_b = (const float*)d_in[4];
  const float* proj_w = (const float*)d_in[5];
  const float* proj_b = (const float*)d_in[6];

  char* p = (char*)d_ws;
  unsigned short* Xb = (unsigned short*)p;       p += (size_t)SEQ * DIM * 2;
  unsigned short* Wq = (unsigned short*)p;       p += (size_t)TDIM * DIM * 2;
  unsigned short* Wp = (unsigned short*)p;       p += (size_t)DIM * DIM * 2;
  float* ct = (float*)p;                         p += (size_t)SEQ * HD * 4;
  float* st = (float*)p;                         p += (size_t)SEQ * HD * 4;
  unsigned short* Y = (unsigned short*)p;        p += (size_t)SEQ * TDIM * 2;
  unsigned short* Qr = (unsigned short*)p;       p += (size_t)NH * SEQ * HQ * 2;
  unsigned short* Kr = (unsigned short*)p;       p += (size_t)NH * SEQ * HQ * 2;
  unsigned short* Vp = (unsigned short*)p;       p += (size_t)NH * HD * SEQ * 2;
  unsigned short* Ob = (unsigned short*)p;       p += (size_t)SEQ * DIM * 2;

  {
    int n4 = SEQ * DIM / 4;
    cvt_bf16<<<(n4 + 255) / 256, 256, 0, stream>>>(hidden, Xb, n4);
  }
  {
    int n4 = TDIM * DIM / 4;
    cvt_bf16<<<(n4 + 255) / 256, 256, 0, stream>>>(qkv_w, Wq, n4);
  }
  {
    int n4 = DIM * DIM / 4;
    cvt_bf16<<<(n4 + 255) / 256, 256, 0, stream>>>(proj_w, Wp, n4);
  }
  {
    int n = SEQ * HD;
    trig_tab<<<(n + 255) / 256, 256, 0, stream>>>(rope, ct, st, n);
  }
  gemm_bt<0><<<dim3(TDIM / 128, SEQ / 128), 256, 0, stream>>>(Xb, Wq, qkv_b, Y, SEQ, TDIM, DIM);
  rope_qk2<<<SEQ, 256, 0, stream>>>(Y, ct, st, Qr, Kr);
  vtrans3<<<dim3(NH, SEQ / 64), 256, 0, stream>>>(Y, Vp);
  attn5<<<512, 256, 0, stream>>>(Qr, Kr, Vp, Ob);
  gemm_bt<1><<<dim3(DIM / 128, SEQ / 128), 256, 0, stream>>>(Ob, Wp, proj_b, d_out, SEQ, DIM, DIM);
}

// Round 6
// 257.471 us; speedup vs baseline: 1.1499x; 1.1499x over previous
//
#include <hip/hip_runtime.h>

#define SEQ 4096
#define DIM 1280
#define NH 16
#define HD 80
#define HQ 96
#define TDIM 3840

// softmax scale (1/sqrt(80)) * log2(e), folded into Q at repack
#define QSC 0.16129842980505168f

typedef __bf16 bf16x8 __attribute__((ext_vector_type(8)));
typedef __bf16 bf16x4 __attribute__((ext_vector_type(4)));
typedef float f32x4 __attribute__((ext_vector_type(4)));

__device__ __forceinline__ unsigned short f2bf(float f) {
  unsigned int u = __builtin_bit_cast(unsigned int, f);
  u += 0x7FFF + ((u >> 16) & 1);
  return (unsigned short)(u >> 16);
}
__device__ __forceinline__ float bf2f(unsigned short b) {
  unsigned int u = ((unsigned int)b) << 16;
  return __builtin_bit_cast(float, u);
}
__device__ __forceinline__ unsigned int cvtpk(float a, float b) {
  unsigned int r;
  asm("v_cvt_pk_bf16_f32 %0, %1, %2" : "=v"(r) : "v"(a), "v"(b));
  return r;
}

__device__ __forceinline__ void gload_lds16(const void* g, void* l) {
  __builtin_amdgcn_global_load_lds(
      (const __attribute__((address_space(1))) unsigned int*)g,
      (__attribute__((address_space(3))) unsigned int*)l, 16, 0, 0);
}

// ---------------- fp32 -> bf16 convert (vectorized) ----------------
__global__ void cvt_bf16(const float* __restrict__ in, unsigned short* __restrict__ out, int n4) {
  int i = blockIdx.x * 256 + threadIdx.x;
  if (i >= n4) return;
  float4 f = ((const float4*)in)[i];
  ushort4 o;
  o.x = f2bf(f.x); o.y = f2bf(f.y); o.z = f2bf(f.z); o.w = f2bf(f.w);
  ((ushort4*)out)[i] = o;
}

// ---------------- cos/sin table ----------------
__global__ void trig_tab(const float* __restrict__ rope, float* __restrict__ ct,
                         float* __restrict__ st, int n) {
  int i = blockIdx.x * 256 + threadIdx.x;
  if (i >= n) return;
  float v = rope[i];
  ct[i] = cosf(v);
  st[i] = sinf(v);
}

// ---------------- GEMM: C = A(MxK) @ B(NxK)^T + bias ----------------
template <int F32OUT>
__global__ __launch_bounds__(256) void gemm_bt(const unsigned short* __restrict__ A,
                                               const unsigned short* __restrict__ B,
                                               const float* __restrict__ bias,
                                               void* __restrict__ Cout, int M, int N, int K) {
  __shared__ unsigned short As[4096];
  __shared__ unsigned short Bs[4096];
  const int t = threadIdx.x;
  const int l = t & 63, w = t >> 6;
  const int row16 = l & 15, kg = l >> 4;
  const int brow = blockIdx.y * 128, bcol = blockIdx.x * 128;
  const int wr = w >> 1, wc = w & 1;
  f32x4 acc[4][4] = {};
  const size_t Ks = (size_t)K;
  const unsigned short* Ag = A + (brow + (t >> 2)) * Ks + (t & 3) * 8;
  const unsigned short* Bg = B + (bcol + (t >> 2)) * Ks + (t & 3) * 8;
  unsigned short* AsW = As + w * 512;
  unsigned short* BsW = Bs + w * 512;
  const int nk = K >> 5;
  for (int kt = 0; kt < nk; ++kt) {
    const unsigned short* a = Ag + kt * 32;
    const unsigned short* b = Bg + kt * 32;
    gload_lds16(a, AsW);
    gload_lds16(a + 64 * Ks, AsW + 2048);
    gload_lds16(b, BsW);
    gload_lds16(b + 64 * Ks, BsW + 2048);
    __syncthreads();
    bf16x8 af[4], bfr[4];
#pragma unroll
    for (int m = 0; m < 4; ++m)
      af[m] = *(const bf16x8*)&As[(wr * 64 + m * 16 + row16) * 32 + kg * 8];
#pragma unroll
    for (int n = 0; n < 4; ++n)
      bfr[n] = *(const bf16x8*)&Bs[(wc * 64 + n * 16 + row16) * 32 + kg * 8];
#pragma unroll
    for (int m = 0; m < 4; ++m)
#pragma unroll
      for (int n = 0; n < 4; ++n)
        acc[m][n] = __builtin_amdgcn_mfma_f32_16x16x32_bf16(af[m], bfr[n], acc[m][n], 0, 0, 0);
    __syncthreads();
  }
#pragma unroll
  for (int n = 0; n < 4; ++n) {
    const int col = bcol + wc * 64 + n * 16 + row16;
    const float bv = bias[col];
#pragma unroll
    for (int m = 0; m < 4; ++m) {
      const int row = brow + wr * 64 + m * 16 + kg * 4;
#pragma unroll
      for (int r = 0; r < 4; ++r) {
        float v = acc[m][n][r] + bv;
        if (F32OUT)
          ((float*)Cout)[(size_t)(row + r) * N + col] = v;
        else
          ((unsigned short*)Cout)[(size_t)(row + r) * N + col] = f2bf(v);
      }
    }
  }
}

// ---------------- RoPE + repack Q,K -> [h][s][96]; Q pre-scaled ----------------
__global__ __launch_bounds__(256) void rope_qk2(const unsigned short* __restrict__ Y,
                                                const float* __restrict__ ct,
                                                const float* __restrict__ st,
                                                unsigned short* __restrict__ Qr,
                                                unsigned short* __restrict__ Kr) {
  const int s = blockIdx.x, tid = threadIdx.x;
  const unsigned short* yq = Y + (size_t)s * TDIM;
  const unsigned short* yk = yq + DIM;
  for (int i = tid; i < 640; i += 256) {
    const int h = i / 40, j = i - h * 40;
    const float c0 = ct[s * HD + j], c1 = ct[s * HD + j + 40];
    const float s0 = st[s * HD + j], s1 = st[s * HD + j + 40];
    const float q0 = bf2f(yq[h * HD + j]), q1 = bf2f(yq[h * HD + j + 40]);
    const float k0 = bf2f(yk[h * HD + j]), k1 = bf2f(yk[h * HD + j + 40]);
    const size_t o = ((size_t)h * SEQ + s) * HQ;
    Qr[o + j] = f2bf((q0 * c0 - q1 * s0) * QSC);
    Qr[o + j + 40] = f2bf((q1 * c1 + q0 * s1) * QSC);
    Kr[o + j] = f2bf(k0 * c0 - k1 * s0);
    Kr[o + j + 40] = f2bf(k1 * c1 + k0 * s1);
  }
  {  // zero pad d = 80..95 for all 16 heads
    const int h = tid >> 4, dp = 80 + (tid & 15);
    const size_t o = ((size_t)h * SEQ + s) * HQ + dp;
    Qr[o] = 0;
    Kr[o] = 0;
  }
}

// ---------------- V transpose -> permuted image Vp[h][d][4096] ----------------
__global__ __launch_bounds__(256) void vtrans3(const unsigned short* __restrict__ Y,
                                               unsigned short* __restrict__ Vp) {
  __shared__ unsigned short tile[64][128];
  const int h = blockIdx.x, s0 = blockIdx.y * 64, tid = threadIdx.x;
  const unsigned short* src = Y + 2 * DIM + h * HD;
  for (int u = tid; u < 640; u += 256) {
    const int s = u / 10, j = u - s * 10;
    uint4 v = *(const uint4*)(src + (size_t)(s0 + s) * TDIM + j * 8);
    *(uint4*)&tile[s][(j ^ ((s >> 3) & 7)) << 3] = v;
  }
  __syncthreads();
  for (int u = tid; u < 640; u += 256) {
    const int d = u >> 3, g = u & 7;
    const int gl = g ^ (d & 7);
    const int base_s = (gl & 1) * 32 + (gl >> 1) * 4;
    unsigned short tmp[8];
#pragma unroll
    for (int sub = 0; sub < 8; ++sub) {
      const int s = base_s + (sub >> 2) * 16 + (sub & 3);
      tmp[sub] = tile[s][(((d >> 3) ^ ((s >> 3) & 7)) << 3) + (d & 7)];
    }
    *(uint4*)(Vp + (size_t)(h * HD + d) * SEQ + s0 + g * 8) = *(uint4*)tmp;
  }
}

// ---------------- Flash attention v6: ring-3 staging, counted vmcnt ----------------
// 4 waves x 32 q; grid 512 blocks; h = bid&15 (XCD affinity).
// K LDS chunk-major [12 ci][64 s][16B]; V from pre-permuted Vp image.
// Staging issued 2 tiles ahead; raw s_barrier + counted vmcnt (never 0 in steady
// state) so loads stay in flight across barriers (T4).
__global__ __launch_bounds__(256, 2) void attn6(const unsigned short* __restrict__ Qr,
                                                const unsigned short* __restrict__ Kr,
                                                const unsigned short* __restrict__ Vp,
                                                unsigned short* __restrict__ Ob) {
  constexpr int KBYT = 12288;
  constexpr int VBYT = 10240;
  constexpr int BUFB = KBYT + VBYT;  // 22528
  constexpr int NT = SEQ / 64;       // 64 tiles
  __shared__ char smem[3 * BUFB];

  const int tid = threadIdx.x;
  const int l = tid & 63, w = tid >> 6;
  const int row16 = l & 15, kg = l >> 4;
  const int bid = blockIdx.x;
  const int h = bid & 15;
  const int q0 = (bid >> 4) * 128 + w * 32;
  const size_t hs = (size_t)h * SEQ;
  const bool loww = (w < 2);  // waves 0,1 issue 6 stage-loads, waves 2,3 issue 5

  const unsigned short* Qh = Qr + hs * HQ;
  const char* Kh = (const char*)(Kr + hs * HQ);
  const char* Vh = (const char*)(Vp + (size_t)h * HD * SEQ);

  // staging: 1408 16B-units (768 K + 640 V); unit u = tid + 256*i
  unsigned soff[6], sdst[6];
  bool isk[6];
  const int cnt = (tid < 128) ? 6 : 5;
#pragma unroll
  for (int i = 0; i < 6; ++i) {
    const int u = tid + 256 * i;
    if (u < 768) {
      soff[i] = (u & 63) * 192 + (u >> 6) * 16;
      isk[i] = true;
    } else {
      const int v = u - 768;
      soff[i] = (v >> 3) * 8192 + (v & 7) * 16;
      isk[i] = false;
    }
    sdst[i] = u << 4;
  }
  auto STAGE = [&](int t, int bb) {
    const char* kb = Kh + (size_t)t * 12288;
    const char* vb = Vh + (size_t)t * 128;
#pragma unroll
    for (int i = 0; i < 6; ++i)
      if (i < cnt) gload_lds16((isk[i] ? kb : vb) + soff[i], smem + bb + sdst[i]);
  };

  // LDS read bases (tile-invariant)
  const int kbase = row16 * 16;  // + (4c+kg)*1024 + nb*256
  int vb_[2];
#pragma unroll
  for (int ks = 0; ks < 2; ++ks)
    vb_[ks] = KBYT + row16 * 128 + ((((kg << 1) | ks) ^ (row16 & 7)) << 4);  // + n5*2048

  // Q fragments (B-operand of swapped QK^T): q = q0 + qb*16 + row16
  bf16x8 qf[2][3];
#pragma unroll
  for (int qb = 0; qb < 2; ++qb)
#pragma unroll
    for (int c = 0; c < 3; ++c)
      qf[qb][c] = *(const bf16x8*)&Qh[(size_t)(q0 + qb * 16 + row16) * HQ + c * 32 + kg * 8];
  // Force the compiler's vmcnt wait for qf HERE (pre-pipeline), not inside the loop.
  asm volatile("" ::"v"(qf[0][0]), "v"(qf[0][1]), "v"(qf[0][2]));
  asm volatile("" ::"v"(qf[1][0]), "v"(qf[1][1]), "v"(qf[1][2]));

  union { bf16x8 v; unsigned int u[4]; } ones;
  ones.u[0] = ones.u[1] = ones.u[2] = ones.u[3] = 0x3F803F80u;

  float m_run[2] = {-3.0e38f, -3.0e38f};
  f32x4 oacc[2][6] = {};  // [qb][d-block 0..4, 5 = row-sum l]

  auto COMPUTE = [&](const char* B) {
    // ---- QK^T: per d-chunk c, load 4 K-frags then 8 MFMAs ----
    f32x4 sacc[2][4] = {};
#pragma unroll
    for (int c = 0; c < 3; ++c) {
      bf16x8 kf[4];
      const char* kc = B + (4 * c + kg) * 1024 + kbase;
#pragma unroll
      for (int nb = 0; nb < 4; ++nb) kf[nb] = *(const bf16x8*)(kc + nb * 256);
      __builtin_amdgcn_s_setprio(1);
#pragma unroll
      for (int qb = 0; qb < 2; ++qb)
#pragma unroll
        for (int nb = 0; nb < 4; ++nb)
          sacc[qb][nb] =
              __builtin_amdgcn_mfma_f32_16x16x32_bf16(kf[nb], qf[qb][c], sacc[qb][nb], 0, 0, 0);
      __builtin_amdgcn_s_setprio(0);
    }
    // ---- V fragments (one b128 per (n5, ks)) ----
    bf16x8 vf[5][2];
#pragma unroll
    for (int n5 = 0; n5 < 5; ++n5)
#pragma unroll
      for (int ks = 0; ks < 2; ++ks) vf[n5][ks] = *(const bf16x8*)(B + vb_[ks] + n5 * 2048);
    // ---- per-lane softmax (q = row16), cross-lane only over kg ----
    float pmax[2];
#pragma unroll
    for (int qb = 0; qb < 2; ++qb) {
      float a0 = fmaxf(fmaxf(sacc[qb][0][0], sacc[qb][0][1]), fmaxf(sacc[qb][0][2], sacc[qb][0][3]));
      float a1 = fmaxf(fmaxf(sacc[qb][1][0], sacc[qb][1][1]), fmaxf(sacc[qb][1][2], sacc[qb][1][3]));
      float a2 = fmaxf(fmaxf(sacc[qb][2][0], sacc[qb][2][1]), fmaxf(sacc[qb][2][2], sacc[qb][2][3]));
      float a3 = fmaxf(fmaxf(sacc[qb][3][0], sacc[qb][3][1]), fmaxf(sacc[qb][3][2], sacc[qb][3][3]));
      float m0 = fmaxf(fmaxf(a0, a1), fmaxf(a2, a3));
      m0 = fmaxf(m0, __shfl_xor(m0, 16, 64));
      m0 = fmaxf(m0, __shfl_xor(m0, 32, 64));
      pmax[qb] = m0;
    }
    if (!__all((pmax[0] - m_run[0] <= 8.0f) & (pmax[1] - m_run[1] <= 8.0f))) {
#pragma unroll
      for (int qb = 0; qb < 2; ++qb) {
        const float mn = fmaxf(m_run[qb], pmax[qb]);
        const float fac = __builtin_amdgcn_exp2f(m_run[qb] - mn);
        m_run[qb] = mn;
#pragma unroll
        for (int n6 = 0; n6 < 6; ++n6)
#pragma unroll
          for (int r = 0; r < 4; ++r) oacc[qb][n6][r] *= fac;
      }
    }
#pragma unroll
    for (int qb = 0; qb < 2; ++qb)
#pragma unroll
      for (int nb = 0; nb < 4; ++nb)
#pragma unroll
        for (int r = 0; r < 4; ++r)
          sacc[qb][nb][r] = __builtin_amdgcn_exp2f(sacc[qb][nb][r] - m_run[qb]);
    // ---- pack P -> bf16 (k-map matches Vp image) and PV + row-sum ----
    __builtin_amdgcn_s_setprio(1);
#pragma unroll
    for (int qb = 0; qb < 2; ++qb)
#pragma unroll
      for (int ks = 0; ks < 2; ++ks) {
        union { bf16x8 v; unsigned int u[4]; } pf;
        pf.u[0] = cvtpk(sacc[qb][2 * ks][0], sacc[qb][2 * ks][1]);
        pf.u[1] = cvtpk(sacc[qb][2 * ks][2], sacc[qb][2 * ks][3]);
        pf.u[2] = cvtpk(sacc[qb][2 * ks + 1][0], sacc[qb][2 * ks + 1][1]);
        pf.u[3] = cvtpk(sacc[qb][2 * ks + 1][2], sacc[qb][2 * ks + 1][3]);
#pragma unroll
        for (int n5 = 0; n5 < 5; ++n5)
          oacc[qb][n5] =
              __builtin_amdgcn_mfma_f32_16x16x32_bf16(vf[n5][ks], pf.v, oacc[qb][n5], 0, 0, 0);
        oacc[qb][5] = __builtin_amdgcn_mfma_f32_16x16x32_bf16(ones.v, pf.v, oacc[qb][5], 0, 0, 0);
      }
    __builtin_amdgcn_s_setprio(0);
  };

  // ---- prologue: fill stages for tiles 0 and 1 ----
  STAGE(0, 0);
  STAGE(1, BUFB);

  int cur = 0;                     // buffer index of tile t
  // main loop: t = 0..NT-3, always stages t+2 (2 stages stay in flight)
#pragma unroll 1
  for (int t = 0; t < NT - 2; ++t) {
    const int sb = (cur == 0) ? 2 : (cur - 1);  // (t+2)%3
    STAGE(t + 2, sb * BUFB);
    // ready-wait for stage(t): 2 younger stages may remain outstanding
    if (loww)
      asm volatile("s_waitcnt vmcnt(12)" ::: "memory");
    else
      asm volatile("s_waitcnt vmcnt(10)" ::: "memory");
    __builtin_amdgcn_s_barrier();
    __builtin_amdgcn_sched_barrier(0);
    COMPUTE(smem + cur * BUFB);
    asm volatile("" ::: "memory");
    __builtin_amdgcn_s_barrier();  // frees buffer cur for stage(t+3)
    cur = (cur == 2) ? 0 : (cur + 1);
  }
  // tail t = NT-2: one stage (NT-1) still in flight
  if (loww)
    asm volatile("s_waitcnt vmcnt(6)" ::: "memory");
  else
    asm volatile("s_waitcnt vmcnt(5)" ::: "memory");
  __builtin_amdgcn_s_barrier();
  __builtin_amdgcn_sched_barrier(0);
  COMPUTE(smem + cur * BUFB);
  asm volatile("" ::: "memory");
  __builtin_amdgcn_s_barrier();
  cur = (cur == 2) ? 0 : (cur + 1);
  // tail t = NT-1: drain fully
  asm volatile("s_waitcnt vmcnt(0)" ::: "memory");
  __builtin_amdgcn_s_barrier();
  __builtin_amdgcn_sched_barrier(0);
  COMPUTE(smem + cur * BUFB);

  // ---- epilogue: d = n5*16 + kg*4 + r, q = q0 + qb*16 + row16 ----
#pragma unroll
  for (int qb = 0; qb < 2; ++qb) {
    const float rl = 1.0f / oacc[qb][5][0];
    unsigned short* orow = Ob + (size_t)(q0 + qb * 16 + row16) * DIM + h * HD + kg * 4;
#pragma unroll
    for (int n5 = 0; n5 < 5; ++n5) {
      ushort4 o;
      o.x = f2bf(oacc[qb][n5][0] * rl);
      o.y = f2bf(oacc[qb][n5][1] * rl);
      o.z = f2bf(oacc[qb][n5][2] * rl);
      o.w = f2bf(oacc[qb][n5][3] * rl);
      *(ushort4*)(orow + n5 * 16) = o;
    }
  }
}

// ---------------- host ----------------
extern "C" void kernel_launch(void* const* d_in, const int* in_sizes, int n_in, void* d_out,
                              int out_size, void* d_ws, size_t ws_size, hipStream_t stream) {
  (void)in_sizes; (void)n_in; (void)out_size; (void)ws_size;
  const float* hidden = (const float*)d_in[0];
  const float* rope = (const float*)d_in[2];
  const float* qkv_w = (const float*)d_in[3];
  const float* qkv_b = (const float*)d_in[4];
  const float* proj_w = (const float*)d_in[5];
  const float* proj_b = (const float*)d_in[6];

  char* p = (char*)d_ws;
  unsigned short* Xb = (unsigned short*)p;       p += (size_t)SEQ * DIM * 2;
  unsigned short* Wq = (unsigned short*)p;       p += (size_t)TDIM * DIM * 2;
  unsigned short* Wp = (unsigned short*)p;       p += (size_t)DIM * DIM * 2;
  float* ct = (float*)p;                         p += (size_t)SEQ * HD * 4;
  float* st = (float*)p;                         p += (size_t)SEQ * HD * 4;
  unsigned short* Y = (unsigned short*)p;        p += (size_t)SEQ * TDIM * 2;
  unsigned short* Qr = (unsigned short*)p;       p += (size_t)NH * SEQ * HQ * 2;
  unsigned short* Kr = (unsigned short*)p;       p += (size_t)NH * SEQ * HQ * 2;
  unsigned short* Vp = (unsigned short*)p;       p += (size_t)NH * HD * SEQ * 2;
  unsigned short* Ob = (unsigned short*)p;       p += (size_t)SEQ * DIM * 2;

  {
    int n4 = SEQ * DIM / 4;
    cvt_bf16<<<(n4 + 255) / 256, 256, 0, stream>>>(hidden, Xb, n4);
  }
  {
    int n4 = TDIM * DIM / 4;
    cvt_bf16<<<(n4 + 255) / 256, 256, 0, stream>>>(qkv_w, Wq, n4);
  }
  {
    int n4 = DIM * DIM / 4;
    cvt_bf16<<<(n4 + 255) / 256, 256, 0, stream>>>(proj_w, Wp, n4);
  }
  {
    int n = SEQ * HD;
    trig_tab<<<(n + 255) / 256, 256, 0, stream>>>(rope, ct, st, n);
  }
  gemm_bt<0><<<dim3(TDIM / 128, SEQ / 128), 256, 0, stream>>>(Xb, Wq, qkv_b, Y, SEQ, TDIM, DIM);
  rope_qk2<<<SEQ, 256, 0, stream>>>(Y, ct, st, Qr, Kr);
  vtrans3<<<dim3(NH, SEQ / 64), 256, 0, stream>>>(Y, Vp);
  attn6<<<512, 256, 0, stream>>>(Qr, Kr, Vp, Ob);
  gemm_bt<1><<<dim3(DIM / 128, SEQ / 128), 256, 0, stream>>>(Ob, Wp, proj_b, d_out, SEQ, DIM, DIM);
}

// Round 7
// 239.261 us; speedup vs baseline: 1.2375x; 1.0761x over previous
//
#include <hip/hip_runtime.h>

#define SEQ 4096
#define DIM 1280
#define NH 16
#define HD 80
#define HQ 96
#define TDIM 3840

// softmax scale (1/sqrt(80)) * log2(e), folded into Q at repack
#define QSC 0.16129842980505168f

typedef __bf16 bf16x8 __attribute__((ext_vector_type(8)));
typedef __bf16 bf16x4 __attribute__((ext_vector_type(4)));
typedef float f32x4 __attribute__((ext_vector_type(4)));

__device__ __forceinline__ unsigned short f2bf(float f) {
  unsigned int u = __builtin_bit_cast(unsigned int, f);
  u += 0x7FFF + ((u >> 16) & 1);
  return (unsigned short)(u >> 16);
}
__device__ __forceinline__ float bf2f(unsigned short b) {
  unsigned int u = ((unsigned int)b) << 16;
  return __builtin_bit_cast(float, u);
}
__device__ __forceinline__ unsigned int cvtpk(float a, float b) {
  unsigned int r;
  asm("v_cvt_pk_bf16_f32 %0, %1, %2" : "=v"(r) : "v"(a), "v"(b));
  return r;
}

__device__ __forceinline__ void gload_lds16(const void* g, void* l) {
  __builtin_amdgcn_global_load_lds(
      (const __attribute__((address_space(1))) unsigned int*)g,
      (__attribute__((address_space(3))) unsigned int*)l, 16, 0, 0);
}

// ---------------- fused prep: fp32->bf16 x3 + cos/sin table ----------------
__global__ __launch_bounds__(256) void prep(const float* __restrict__ X,
                                            const float* __restrict__ Wq,
                                            const float* __restrict__ Wp,
                                            const float* __restrict__ rope,
                                            unsigned short* __restrict__ Xb,
                                            unsigned short* __restrict__ Wqb,
                                            unsigned short* __restrict__ Wpb,
                                            float* __restrict__ ct, float* __restrict__ st) {
  constexpr int N0 = SEQ * DIM / 4;
  constexpr int N1 = TDIM * DIM / 4;
  constexpr int N2 = DIM * DIM / 4;
  constexpr int N3 = SEQ * HD / 4;
  const int stride = gridDim.x * 256;
  for (int i = blockIdx.x * 256 + threadIdx.x; i < N0 + N1 + N2 + N3; i += stride) {
    if (i < N0 + N1 + N2) {
      const float4* src;
      unsigned short* dst;
      int j;
      if (i < N0) {
        src = (const float4*)X; dst = Xb; j = i;
      } else if (i < N0 + N1) {
        src = (const float4*)Wq; dst = Wqb; j = i - N0;
      } else {
        src = (const float4*)Wp; dst = Wpb; j = i - N0 - N1;
      }
      float4 f = src[j];
      ushort4 o;
      o.x = f2bf(f.x); o.y = f2bf(f.y); o.z = f2bf(f.z); o.w = f2bf(f.w);
      ((ushort4*)dst)[j] = o;
    } else {
      const int j = i - N0 - N1 - N2;
      float4 v = ((const float4*)rope)[j];
      float4 c, s;
      c.x = cosf(v.x); c.y = cosf(v.y); c.z = cosf(v.z); c.w = cosf(v.w);
      s.x = sinf(v.x); s.y = sinf(v.y); s.z = sinf(v.z); s.w = sinf(v.w);
      ((float4*)ct)[j] = c;
      ((float4*)st)[j] = s;
    }
  }
}

// ---------------- GEMM: C = A(MxK) @ B(NxK)^T + bias ----------------
// 128x128 tile, BK=32, 4 waves; ring-2 LDS + counted vmcnt (loads stay in
// flight across barriers -- T4).
template <int F32OUT>
__global__ __launch_bounds__(256) void gemm_bt(const unsigned short* __restrict__ A,
                                               const unsigned short* __restrict__ B,
                                               const float* __restrict__ bias,
                                               void* __restrict__ Cout, int M, int N, int K) {
  __shared__ unsigned short As[2][4096];
  __shared__ unsigned short Bs[2][4096];
  const int t = threadIdx.x;
  const int l = t & 63, w = t >> 6;
  const int row16 = l & 15, kg = l >> 4;
  const int brow = blockIdx.y * 128, bcol = blockIdx.x * 128;
  const int wr = w >> 1, wc = w & 1;
  f32x4 acc[4][4] = {};
  const size_t Ks = (size_t)K;
  const unsigned short* Ag = A + (brow + (t >> 2)) * Ks + (t & 3) * 8;
  const unsigned short* Bg = B + (bcol + (t >> 2)) * Ks + (t & 3) * 8;
  const int woff = w * 512;
  const int nk = K >> 5;

  auto SG = [&](int kt, int b) {
    const unsigned short* a = Ag + kt * 32;
    const unsigned short* bp = Bg + kt * 32;
    gload_lds16(a, &As[b][woff]);
    gload_lds16(a + 64 * Ks, &As[b][woff + 2048]);
    gload_lds16(bp, &Bs[b][woff]);
    gload_lds16(bp + 64 * Ks, &Bs[b][woff + 2048]);
  };
  auto COMP = [&](int b) {
    bf16x8 af[4], bfr[4];
#pragma unroll
    for (int m = 0; m < 4; ++m)
      af[m] = *(const bf16x8*)&As[b][(wr * 64 + m * 16 + row16) * 32 + kg * 8];
#pragma unroll
    for (int n = 0; n < 4; ++n)
      bfr[n] = *(const bf16x8*)&Bs[b][(wc * 64 + n * 16 + row16) * 32 + kg * 8];
#pragma unroll
    for (int m = 0; m < 4; ++m)
#pragma unroll
      for (int n = 0; n < 4; ++n)
        acc[m][n] = __builtin_amdgcn_mfma_f32_16x16x32_bf16(af[m], bfr[n], acc[m][n], 0, 0, 0);
  };

  SG(0, 0);
#pragma unroll 1
  for (int kt = 0; kt < nk - 1; ++kt) {
    SG(kt + 1, (kt + 1) & 1);
    asm volatile("s_waitcnt vmcnt(4)" ::: "memory");
    __builtin_amdgcn_s_barrier();
    __builtin_amdgcn_sched_barrier(0);
    COMP(kt & 1);
    asm volatile("" ::: "memory");
    __builtin_amdgcn_s_barrier();
  }
  asm volatile("s_waitcnt vmcnt(0)" ::: "memory");
  __builtin_amdgcn_s_barrier();
  __builtin_amdgcn_sched_barrier(0);
  COMP((nk - 1) & 1);

#pragma unroll
  for (int n = 0; n < 4; ++n) {
    const int col = bcol + wc * 64 + n * 16 + row16;
    const float bv = bias[col];
#pragma unroll
    for (int m = 0; m < 4; ++m) {
      const int row = brow + wr * 64 + m * 16 + kg * 4;
#pragma unroll
      for (int r = 0; r < 4; ++r) {
        float v = acc[m][n][r] + bv;
        if (F32OUT)
          ((float*)Cout)[(size_t)(row + r) * N + col] = v;
        else
          ((unsigned short*)Cout)[(size_t)(row + r) * N + col] = f2bf(v);
      }
    }
  }
}

// ---------------- RoPE + repack Q,K -> [h][s][96]; Q pre-scaled ----------------
__global__ __launch_bounds__(256) void rope_qk2(const unsigned short* __restrict__ Y,
                                                const float* __restrict__ ct,
                                                const float* __restrict__ st,
                                                unsigned short* __restrict__ Qr,
                                                unsigned short* __restrict__ Kr) {
  const int s = blockIdx.x, tid = threadIdx.x;
  const unsigned short* yq = Y + (size_t)s * TDIM;
  const unsigned short* yk = yq + DIM;
  for (int i = tid; i < 640; i += 256) {
    const int h = i / 40, j = i - h * 40;
    const float c0 = ct[s * HD + j], c1 = ct[s * HD + j + 40];
    const float s0 = st[s * HD + j], s1 = st[s * HD + j + 40];
    const float q0 = bf2f(yq[h * HD + j]), q1 = bf2f(yq[h * HD + j + 40]);
    const float k0 = bf2f(yk[h * HD + j]), k1 = bf2f(yk[h * HD + j + 40]);
    const size_t o = ((size_t)h * SEQ + s) * HQ;
    Qr[o + j] = f2bf((q0 * c0 - q1 * s0) * QSC);
    Qr[o + j + 40] = f2bf((q1 * c1 + q0 * s1) * QSC);
    Kr[o + j] = f2bf(k0 * c0 - k1 * s0);
    Kr[o + j + 40] = f2bf(k1 * c1 + k0 * s1);
  }
  {  // zero pad d = 80..95 for all 16 heads
    const int h = tid >> 4, dp = 80 + (tid & 15);
    const size_t o = ((size_t)h * SEQ + s) * HQ + dp;
    Qr[o] = 0;
    Kr[o] = 0;
  }
}

// ---------------- V transpose -> permuted image Vp[h][d][4096] ----------------
__global__ __launch_bounds__(256) void vtrans3(const unsigned short* __restrict__ Y,
                                               unsigned short* __restrict__ Vp) {
  __shared__ unsigned short tile[64][128];
  const int h = blockIdx.x, s0 = blockIdx.y * 64, tid = threadIdx.x;
  const unsigned short* src = Y + 2 * DIM + h * HD;
  for (int u = tid; u < 640; u += 256) {
    const int s = u / 10, j = u - s * 10;
    uint4 v = *(const uint4*)(src + (size_t)(s0 + s) * TDIM + j * 8);
    *(uint4*)&tile[s][(j ^ ((s >> 3) & 7)) << 3] = v;
  }
  __syncthreads();
  for (int u = tid; u < 640; u += 256) {
    const int d = u >> 3, g = u & 7;
    const int gl = g ^ (d & 7);
    const int base_s = (gl & 1) * 32 + (gl >> 1) * 4;
    unsigned short tmp[8];
#pragma unroll
    for (int sub = 0; sub < 8; ++sub) {
      const int s = base_s + (sub >> 2) * 16 + (sub & 3);
      tmp[sub] = tile[s][(((d >> 3) ^ ((s >> 3) & 7)) << 3) + (d & 7)];
    }
    *(uint4*)(Vp + (size_t)(h * HD + d) * SEQ + s0 + g * 8) = *(uint4*)tmp;
  }
}

// ---------------- Flash attention v7: ring-3 counted vmcnt + fast-path softmax ----
__global__ __launch_bounds__(256, 2) void attn7(const unsigned short* __restrict__ Qr,
                                                const unsigned short* __restrict__ Kr,
                                                const unsigned short* __restrict__ Vp,
                                                unsigned short* __restrict__ Ob) {
  constexpr int KBYT = 12288;
  constexpr int VBYT = 10240;
  constexpr int BUFB = KBYT + VBYT;  // 22528
  constexpr int NT = SEQ / 64;       // 64 tiles
  __shared__ char smem[3 * BUFB];

  const int tid = threadIdx.x;
  const int l = tid & 63, w = tid >> 6;
  const int row16 = l & 15, kg = l >> 4;
  const int bid = blockIdx.x;
  const int h = bid & 15;
  const int q0 = (bid >> 4) * 128 + w * 32;
  const size_t hs = (size_t)h * SEQ;
  const bool loww = (w < 2);

  const unsigned short* Qh = Qr + hs * HQ;
  const char* Kh = (const char*)(Kr + hs * HQ);
  const char* Vh = (const char*)(Vp + (size_t)h * HD * SEQ);

  // staging: 1408 16B-units (768 K + 640 V); unit u = tid + 256*i
  unsigned soff[6], sdst[6];
  bool isk[6];
  const int cnt = (tid < 128) ? 6 : 5;
#pragma unroll
  for (int i = 0; i < 6; ++i) {
    const int u = tid + 256 * i;
    if (u < 768) {
      soff[i] = (u & 63) * 192 + (u >> 6) * 16;
      isk[i] = true;
    } else {
      const int v = u - 768;
      soff[i] = (v >> 3) * 8192 + (v & 7) * 16;
      isk[i] = false;
    }
    sdst[i] = u << 4;
  }
  auto STAGE = [&](int t, int bb) {
    const char* kb = Kh + (size_t)t * 12288;
    const char* vb = Vh + (size_t)t * 128;
#pragma unroll
    for (int i = 0; i < 6; ++i)
      if (i < cnt) gload_lds16((isk[i] ? kb : vb) + soff[i], smem + bb + sdst[i]);
  };

  // LDS read bases (tile-invariant)
  const int kbase = row16 * 16;  // + (4c+kg)*1024 + nb*256
  int vb_[2];
#pragma unroll
  for (int ks = 0; ks < 2; ++ks)
    vb_[ks] = KBYT + row16 * 128 + ((((kg << 1) | ks) ^ (row16 & 7)) << 4);  // + n5*2048

  // Q fragments (B-operand of swapped QK^T): q = q0 + qb*16 + row16
  bf16x8 qf[2][3];
#pragma unroll
  for (int qb = 0; qb < 2; ++qb)
#pragma unroll
    for (int c = 0; c < 3; ++c)
      qf[qb][c] = *(const bf16x8*)&Qh[(size_t)(q0 + qb * 16 + row16) * HQ + c * 32 + kg * 8];
  // Force the compiler's vmcnt wait for qf HERE (pre-pipeline), not inside the loop.
  asm volatile("" ::"v"(qf[0][0]), "v"(qf[0][1]), "v"(qf[0][2]));
  asm volatile("" ::"v"(qf[1][0]), "v"(qf[1][1]), "v"(qf[1][2]));

  union { bf16x8 v; unsigned int u[4]; } ones;
  ones.u[0] = ones.u[1] = ones.u[2] = ones.u[3] = 0x3F803F80u;

  float m_run[2] = {-3.0e38f, -3.0e38f};
  f32x4 oacc[2][6] = {};  // [qb][d-block 0..4, 5 = row-sum l]

  auto COMPUTE = [&](const char* B) {
    // ---- QK^T: per d-chunk c, load 4 K-frags then 8 MFMAs ----
    f32x4 sacc[2][4] = {};
#pragma unroll
    for (int c = 0; c < 3; ++c) {
      bf16x8 kf[4];
      const char* kc = B + (4 * c + kg) * 1024 + kbase;
#pragma unroll
      for (int nb = 0; nb < 4; ++nb) kf[nb] = *(const bf16x8*)(kc + nb * 256);
      __builtin_amdgcn_s_setprio(1);
#pragma unroll
      for (int qb = 0; qb < 2; ++qb)
#pragma unroll
        for (int nb = 0; nb < 4; ++nb)
          sacc[qb][nb] =
              __builtin_amdgcn_mfma_f32_16x16x32_bf16(kf[nb], qf[qb][c], sacc[qb][nb], 0, 0, 0);
      __builtin_amdgcn_s_setprio(0);
    }
    // ---- V fragments (one b128 per (n5, ks)) ----
    bf16x8 vf[5][2];
#pragma unroll
    for (int n5 = 0; n5 < 5; ++n5)
#pragma unroll
      for (int ks = 0; ks < 2; ++ks) vf[n5][ks] = *(const bf16x8*)(B + vb_[ks] + n5 * 2048);
    // ---- softmax: per-lane local max; cross-lane ONLY when threshold exceeded ----
    float pl[2];
#pragma unroll
    for (int qb = 0; qb < 2; ++qb) {
      float a0 = fmaxf(fmaxf(sacc[qb][0][0], sacc[qb][0][1]), fmaxf(sacc[qb][0][2], sacc[qb][0][3]));
      float a1 = fmaxf(fmaxf(sacc[qb][1][0], sacc[qb][1][1]), fmaxf(sacc[qb][1][2], sacc[qb][1][3]));
      float a2 = fmaxf(fmaxf(sacc[qb][2][0], sacc[qb][2][1]), fmaxf(sacc[qb][2][2], sacc[qb][2][3]));
      float a3 = fmaxf(fmaxf(sacc[qb][3][0], sacc[qb][3][1]), fmaxf(sacc[qb][3][2], sacc[qb][3][3]));
      pl[qb] = fmaxf(fmaxf(a0, a1), fmaxf(a2, a3));
    }
    // fast path: no lane's local max grew past m_run + 8 -> keep m_run, P <= 2^8
    if (!__all((pl[0] - m_run[0] <= 8.0f) & (pl[1] - m_run[1] <= 8.0f))) {
#pragma unroll
      for (int qb = 0; qb < 2; ++qb) {
        float m0 = pl[qb];
        m0 = fmaxf(m0, __shfl_xor(m0, 16, 64));
        m0 = fmaxf(m0, __shfl_xor(m0, 32, 64));
        const float mn = fmaxf(m_run[qb], m0);
        const float fac = __builtin_amdgcn_exp2f(m_run[qb] - mn);
        m_run[qb] = mn;
#pragma unroll
        for (int n6 = 0; n6 < 6; ++n6)
#pragma unroll
          for (int r = 0; r < 4; ++r) oacc[qb][n6][r] *= fac;
      }
    }
#pragma unroll
    for (int qb = 0; qb < 2; ++qb)
#pragma unroll
      for (int nb = 0; nb < 4; ++nb)
#pragma unroll
        for (int r = 0; r < 4; ++r)
          sacc[qb][nb][r] = __builtin_amdgcn_exp2f(sacc[qb][nb][r] - m_run[qb]);
    // ---- pack P -> bf16 (k-map matches Vp image) and PV + row-sum ----
    __builtin_amdgcn_s_setprio(1);
#pragma unroll
    for (int qb = 0; qb < 2; ++qb)
#pragma unroll
      for (int ks = 0; ks < 2; ++ks) {
        union { bf16x8 v; unsigned int u[4]; } pf;
        pf.u[0] = cvtpk(sacc[qb][2 * ks][0], sacc[qb][2 * ks][1]);
        pf.u[1] = cvtpk(sacc[qb][2 * ks][2], sacc[qb][2 * ks][3]);
        pf.u[2] = cvtpk(sacc[qb][2 * ks + 1][0], sacc[qb][2 * ks + 1][1]);
        pf.u[3] = cvtpk(sacc[qb][2 * ks + 1][2], sacc[qb][2 * ks + 1][3]);
#pragma unroll
        for (int n5 = 0; n5 < 5; ++n5)
          oacc[qb][n5] =
              __builtin_amdgcn_mfma_f32_16x16x32_bf16(vf[n5][ks], pf.v, oacc[qb][n5], 0, 0, 0);
        oacc[qb][5] = __builtin_amdgcn_mfma_f32_16x16x32_bf16(ones.v, pf.v, oacc[qb][5], 0, 0, 0);
      }
    __builtin_amdgcn_s_setprio(0);
  };

  // ---- prologue: fill stages for tiles 0 and 1 ----
  STAGE(0, 0);
  STAGE(1, BUFB);

  int cur = 0;
#pragma unroll 1
  for (int t = 0; t < NT - 2; ++t) {
    const int sb = (cur == 0) ? 2 : (cur - 1);  // (t+2)%3
    STAGE(t + 2, sb * BUFB);
    if (loww)
      asm volatile("s_waitcnt vmcnt(12)" ::: "memory");
    else
      asm volatile("s_waitcnt vmcnt(10)" ::: "memory");
    __builtin_amdgcn_s_barrier();
    __builtin_amdgcn_sched_barrier(0);
    COMPUTE(smem + cur * BUFB);
    asm volatile("" ::: "memory");
    __builtin_amdgcn_s_barrier();
    cur = (cur == 2) ? 0 : (cur + 1);
  }
  if (loww)
    asm volatile("s_waitcnt vmcnt(6)" ::: "memory");
  else
    asm volatile("s_waitcnt vmcnt(5)" ::: "memory");
  __builtin_amdgcn_s_barrier();
  __builtin_amdgcn_sched_barrier(0);
  COMPUTE(smem + cur * BUFB);
  asm volatile("" ::: "memory");
  __builtin_amdgcn_s_barrier();
  cur = (cur == 2) ? 0 : (cur + 1);
  asm volatile("s_waitcnt vmcnt(0)" ::: "memory");
  __builtin_amdgcn_s_barrier();
  __builtin_amdgcn_sched_barrier(0);
  COMPUTE(smem + cur * BUFB);

  // ---- epilogue: d = n5*16 + kg*4 + r, q = q0 + qb*16 + row16 ----
#pragma unroll
  for (int qb = 0; qb < 2; ++qb) {
    const float rl = 1.0f / oacc[qb][5][0];
    unsigned short* orow = Ob + (size_t)(q0 + qb * 16 + row16) * DIM + h * HD + kg * 4;
#pragma unroll
    for (int n5 = 0; n5 < 5; ++n5) {
      ushort4 o;
      o.x = f2bf(oacc[qb][n5][0] * rl);
      o.y = f2bf(oacc[qb][n5][1] * rl);
      o.z = f2bf(oacc[qb][n5][2] * rl);
      o.w = f2bf(oacc[qb][n5][3] * rl);
      *(ushort4*)(orow + n5 * 16) = o;
    }
  }
}

// ---------------- host ----------------
extern "C" void kernel_launch(void* const* d_in, const int* in_sizes, int n_in, void* d_out,
                              int out_size, void* d_ws, size_t ws_size, hipStream_t stream) {
  (void)in_sizes; (void)n_in; (void)out_size; (void)ws_size;
  const float* hidden = (const float*)d_in[0];
  const float* rope = (const float*)d_in[2];
  const float* qkv_w = (const float*)d_in[3];
  const float* qkv_b = (const float*)d_in[4];
  const float* proj_w = (const float*)d_in[5];
  const float* proj_b = (const float*)d_in[6];

  char* p = (char*)d_ws;
  unsigned short* Xb = (unsigned short*)p;       p += (size_t)SEQ * DIM * 2;
  unsigned short* Wq = (unsigned short*)p;       p += (size_t)TDIM * DIM * 2;
  unsigned short* Wp = (unsigned short*)p;       p += (size_t)DIM * DIM * 2;
  float* ct = (float*)p;                         p += (size_t)SEQ * HD * 4;
  float* st = (float*)p;                         p += (size_t)SEQ * HD * 4;
  unsigned short* Y = (unsigned short*)p;        p += (size_t)SEQ * TDIM * 2;
  unsigned short* Qr = (unsigned short*)p;       p += (size_t)NH * SEQ * HQ * 2;
  unsigned short* Kr = (unsigned short*)p;       p += (size_t)NH * SEQ * HQ * 2;
  unsigned short* Vp = (unsigned short*)p;       p += (size_t)NH * HD * SEQ * 2;
  unsigned short* Ob = (unsigned short*)p;       p += (size_t)SEQ * DIM * 2;

  prep<<<2048, 256, 0, stream>>>(hidden, qkv_w, proj_w, rope, Xb, Wq, Wp, ct, st);
  gemm_bt<0><<<dim3(TDIM / 128, SEQ / 128), 256, 0, stream>>>(Xb, Wq, qkv_b, Y, SEQ, TDIM, DIM);
  rope_qk2<<<SEQ, 256, 0, stream>>>(Y, ct, st, Qr, Kr);
  vtrans3<<<dim3(NH, SEQ / 64), 256, 0, stream>>>(Y, Vp);
  attn7<<<512, 256, 0, stream>>>(Qr, Kr, Vp, Ob);
  gemm_bt<1><<<dim3(DIM / 128, SEQ / 128), 256, 0, stream>>>(Ob, Wp, proj_b, d_out, SEQ, DIM, DIM);
}